// Round 2
// baseline (436.199 us; speedup 1.0000x reference)
//
#include <hip/hip_runtime.h>
#include <hip/hip_bf16.h>

#define KK 9
#define PADK 4
#define CIN 64
#define COUT 64
#define LSEQ 131072
#define NB 4
#define TILEL 64          // l-extent of a block tile (R2: halved for occupancy)
#define XROWS 72          // TILEL + KK - 1
#define XRS 72            // xt row stride (bf16); 144 B rows, 16B-aligned
#define NTILES 2048       // LSEQ / TILEL
#define NPART 256
#define TPB 4             // tiles per block (prefetch pipeline)
#define GRIDC (NB * NTILES / TPB)   // 2048 blocks -> ~5 resident/CU

typedef __attribute__((ext_vector_type(8))) short v8s;
typedef __attribute__((ext_vector_type(4))) short v4s;
typedef __attribute__((ext_vector_type(4))) float v4f;

__device__ __forceinline__ unsigned short f2bf(float f) {
  __hip_bfloat16 h = __float2bfloat16(f);
  return *reinterpret_cast<unsigned short*>(&h);
}
__device__ __forceinline__ float bf2f(unsigned short s) {
  return __uint_as_float(((unsigned)s) << 16);
}

__device__ __forceinline__ void store_o(float* p, float v) { *p = v; }
__device__ __forceinline__ void store_o(__hip_bfloat16* p, float v) { *p = __float2bfloat16(v); }

// 16-lane (intra-row) sum on the VALU pipe via DPP (replaces ds_bpermute shuffles)
template <int CTRL>
__device__ __forceinline__ float dppadd(float v) {
  int s = __builtin_amdgcn_update_dpp(0, __float_as_int(v), CTRL, 0xF, 0xF, true);
  return v + __int_as_float(s);
}
__device__ __forceinline__ float red16(float v) {
  v = dppadd<0xB1>(v);    // quad_perm [1,0,3,2]  (xor 1)
  v = dppadd<0x4E>(v);    // quad_perm [2,3,0,1]  (xor 2)
  v = dppadd<0x141>(v);   // row_half_mirror      (xor 4)
  v = dppadd<0x140>(v);   // row_mirror           (xor 8)
  return v;
}

// ---------------------------------------------------------------------------
// Repack W[Cout][Cin][K] fp32 -> bf16 A-fragments for mfma_f32_16x16x32_bf16,
// pre-swizzled: frag (k, s, mblk) is 1024 contiguous bytes, lane-major.
// ---------------------------------------------------------------------------
__global__ void wtrans_kernel(const float* __restrict__ W, v8s* __restrict__ Wt) {
  int t = blockIdx.x * 256 + threadIdx.x;
  if (t >= KK * 2 * 4 * 64) return;
  int lane = t & 63;
  int frag = t >> 6;
  int mblk = frag & 3;
  int s    = (frag >> 2) & 1;
  int k    = frag >> 3;
  int m = lane & 15, q = lane >> 4;
  int o = mblk * 16 + m;
  union { v8s v; unsigned short h[8]; } u;
#pragma unroll
  for (int j = 0; j < 8; ++j) {
    int c = 32 * s + q * 8 + j;
    u.h[j] = f2bf(W[(o * CIN + c) * KK + k]);
  }
  Wt[t] = u.v;
}

// ---------------------------------------------------------------------------
// Weighted conv via MFMA, telescoped per-k GEMM decomposition.
// R2: TILEL=64 tiles, TPB=4 pipeline, LDS dbuf 25.9 KB, acc 32 f32/lane
// -> ~5 resident blocks/CU; prefetch of tile t+1 issued before a raw
// s_barrier (vmcnt NOT drained) so HBM latency hides under tile t compute.
// ---------------------------------------------------------------------------
template <typename OutT>
__global__ __launch_bounds__(256, 5)
void conv_kernel(const float* __restrict__ x, const float* __restrict__ coords,
                 const v8s* __restrict__ Wt, OutT* __restrict__ cv,
                 float* __restrict__ stat_sum, float* __restrict__ stat_sq) {
  __shared__ __align__(16) __hip_bfloat16 xt[2][XROWS][XRS]; // 20736 B
  __shared__ float wt[2][KK + 1][TILEL];                     //  5120 B (row 9 = 0)

  const int tid  = threadIdx.x;
  const int wv   = tid >> 6;
  const int wo   = wv & 1;                    // o-half (32 rows)
  const int wl   = wv >> 1;                   // l-half (32 cols)
  const int lane = tid & 63;
  const int m = lane & 15;
  const int q = lane >> 4;

  const int bid = blockIdx.x;                 // 0..2047
  const int b   = bid >> 9;                   // 512 blocks per batch
  const int t0  = (bid & 511) * TPB;          // 4 consecutive tiles (halo L2 reuse)
  const float* xb = x + (b * CIN) * LSEQ;
  const float* cb = coords + (b * 3) * LSEQ;
  OutT* outb = cv + (b * COUT) * LSEQ;

  // staging roles
  const int c4i = tid & 15, c4 = c4i * 4;     // 16 groups of 4 channels
  const int lc  = tid >> 4;                   // l-chunk 0..15 (4 l each)
  const int cn  = tid & 63;                   // coord n
  const int kq  = tid >> 6;                   // k-group: {0,1,2},{3,4,5},{6,7,8},zero-row

  // prefetch registers (live across the compute phase)
  float4 f[4];                                // x main: 4 channels x 4 l
  float4 hx;                                  // halo (tid<128)
  float sx, sy, sz;                           // center coords (kq<3)
  float nx[3], ny[3], nz[3];                  // neighbor coords (3 ks)

  auto prefetch = [&](int tile) {
    const int l0 = tile * TILEL;
#pragma unroll
    for (int t = 0; t < 4; ++t)
      f[t] = *(const float4*)(xb + (c4 + t) * LSEQ + l0 + 4 * lc);
    if (tid < 128) {
      int side = tid >> 6, c = tid & 63;
      hx = make_float4(0.f, 0.f, 0.f, 0.f);
      if (side == 0) {
        if (tile != 0) hx = *(const float4*)(xb + c * LSEQ + l0 - 4);
      } else {
        if (tile != NTILES - 1) hx = *(const float4*)(xb + c * LSEQ + l0 + TILEL);
      }
    }
    if (kq < 3) {
      sx = cb[l0 + cn];
      sy = cb[LSEQ + l0 + cn];
      sz = cb[2 * LSEQ + l0 + cn];
#pragma unroll
      for (int i = 0; i < 3; ++i) {
        int l = l0 + cn + (kq * 3 + i) - PADK;
        float cx = 0.f, cy = 0.f, cz = 0.f;
        if ((unsigned)l < (unsigned)LSEQ) {   // zero-pad like jnp.pad
          cx = cb[l]; cy = cb[LSEQ + l]; cz = cb[2 * LSEQ + l];
        }
        nx[i] = cx; ny[i] = cy; nz[i] = cz;
      }
    }
  };

  prefetch(t0);

#pragma unroll 1
  for (int ti = 0; ti < TPB; ++ti) {
    const int tile = t0 + ti;
    const int l0 = tile * TILEL;
    const int cur = ti & 1;

    // ---- consume prefetched regs -> LDS buf[cur] ----
    {
      const float* fp = (const float*)&f[0];
#pragma unroll
      for (int j = 0; j < 4; ++j) {
        union { v4s v; unsigned short h[4]; } u;
#pragma unroll
        for (int t = 0; t < 4; ++t) u.h[t] = f2bf(fp[4 * t + j]);
        *(v4s*)&xt[cur][4 + 4 * lc + j][c4] = u.v;
      }
      if (tid < 128) {
        int side = tid >> 6, c = tid & 63;
        int rb = side ? (TILEL + PADK) : 0;
        xt[cur][rb + 0][c] = __float2bfloat16(hx.x);
        xt[cur][rb + 1][c] = __float2bfloat16(hx.y);
        xt[cur][rb + 2][c] = __float2bfloat16(hx.z);
        xt[cur][rb + 3][c] = __float2bfloat16(hx.w);
      }
      if (kq < 3) {
#pragma unroll
        for (int i = 0; i < 3; ++i) {
          float dx = nx[i] - sx, dy = ny[i] - sy, dz = nz[i] - sz;
          wt[cur][kq * 3 + i][cn] = __expf(-0.5f * (dx * dx + dy * dy + dz * dz));
        }
      } else {
        wt[cur][KK][cn] = 0.f;                // telescope terminator row
      }
    }

    // ---- issue next tile's global loads; stay in flight across the raw
    //      barrier (no vmcnt drain) and hide under compute ----
    if (ti + 1 < TPB) prefetch(tile + 1);

    asm volatile("s_waitcnt lgkmcnt(0)" ::: "memory");
    __builtin_amdgcn_s_barrier();

    // ---- MFMA main loop (reads buf[cur]) ----
    v4f y[2][2], tot[2][2];                   // [mblk][nbq]
#pragma unroll
    for (int i = 0; i < 2; ++i)
#pragma unroll
      for (int j = 0; j < 2; ++j) {
        y[i][j]   = (v4f){0.f, 0.f, 0.f, 0.f};
        tot[i][j] = (v4f){0.f, 0.f, 0.f, 0.f};
      }

    const v8s* wp = Wt + (wo * 2) * 64 + lane;   // frag(k,s,mb) @ k*512+s*256+mb*64
    const int col0 = wl * 32 + m;
    float wc[2] = { wt[cur][0][col0], wt[cur][0][col0 + 16] };   // rolling w

#pragma unroll 1
    for (int k = 0; k < KK; ++k) {
#pragma unroll
      for (int s = 0; s < 2; ++s) {
        v8s a0 = wp[k * 512 + s * 256];
        v8s a1 = wp[k * 512 + s * 256 + 64];
#pragma unroll
        for (int nbq = 0; nbq < 2; ++nbq) {
          v8s bf = *(const v8s*)&xt[cur][wl * 32 + nbq * 16 + m + k][q * 8 + 32 * s];
          y[0][nbq] = __builtin_amdgcn_mfma_f32_16x16x32_bf16(a0, bf, y[0][nbq], 0, 0, 0);
          y[1][nbq] = __builtin_amdgcn_mfma_f32_16x16x32_bf16(a1, bf, y[1][nbq], 0, 0, 0);
        }
      }
      // telescoping accumulate: d[k] = w[k] - w[k+1] (w[9] = 0)
#pragma unroll
      for (int nbq = 0; nbq < 2; ++nbq) {
        float wn = wt[cur][k + 1][col0 + nbq * 16];
        float d = wc[nbq] - wn;
        wc[nbq] = wn;
#pragma unroll
        for (int mb = 0; mb < 2; ++mb)
#pragma unroll
          for (int r = 0; r < 4; ++r)
            tot[mb][nbq][r] = __builtin_fmaf(d, y[mb][nbq][r], tot[mb][nbq][r]);
      }
    }

    // ---- epilogue: store conv result + per-channel sum/sumsq partials ----
    const int part = tile & (NPART - 1);
#pragma unroll
    for (int mb = 0; mb < 2; ++mb) {
#pragma unroll
      for (int r = 0; r < 4; ++r) {
        int o = wo * 32 + mb * 16 + q * 4 + r;   // C-layout: row = q*4 + reg
        float s1 = 0.f, s2 = 0.f;
#pragma unroll
        for (int nbq = 0; nbq < 2; ++nbq) {
          float v = tot[mb][nbq][r];
          s1 += v;
          s2 += v * v;
          store_o(&outb[o * LSEQ + l0 + wl * 32 + nbq * 16 + m], v); // col = lane&15
        }
        s1 = red16(s1);                          // VALU-pipe DPP reduction
        s2 = red16(s2);
        if (m == 0) {
          atomicAdd(&stat_sum[o * NPART + part], s1);
          atomicAdd(&stat_sq [o * NPART + part], s2);
        }
      }
    }
  }
}

// ---------------------------------------------------------------------------
// BN finalize: scale = gamma*rsqrt(var+eps), shift = beta - mean*scale.
// (Conv bias cancels exactly under training-mode BN, so it is skipped.)
// Stats layout [COUT][NPART] -> contiguous float4 reduction per channel.
// ---------------------------------------------------------------------------
__global__ void finalize_kernel(const float* __restrict__ stat_sum,
                                const float* __restrict__ stat_sq,
                                const float* __restrict__ gamma,
                                const float* __restrict__ beta,
                                float* __restrict__ ss) {
  int o = threadIdx.x;
  const float4* p1 = (const float4*)(stat_sum + o * NPART);
  const float4* p2 = (const float4*)(stat_sq  + o * NPART);
  float s1 = 0.f, s2 = 0.f;
#pragma unroll 4
  for (int p = 0; p < NPART / 4; ++p) {
    float4 a = p1[p]; s1 += (a.x + a.y) + (a.z + a.w);
    float4 c = p2[p]; s2 += (c.x + c.y) + (c.z + c.w);
  }
  const float invN = 1.0f / (float)(NB * LSEQ);
  float mean = s1 * invN;
  float var  = s2 * invN - mean * mean;   // biased, matches jnp.var
  float sc = gamma[o] * rsqrtf(var + 1e-5f);
  ss[o]        = sc;
  ss[COUT + o] = beta[o] - mean * sc;
}

// ---- BN apply + ReLU; one block = 2048 contiguous elems in one channel ----
__global__ __launch_bounds__(256)
void scale_f32_kernel(float* __restrict__ data, const float* __restrict__ ss) {
  const int blk = blockIdx.x;
  const int ch = (blk >> 6) & 63;   // L/2048 = 64 blocks per channel
  const float sc = ss[ch];
  const float sh = ss[COUT + ch];
  const int base = blk * 2048 + threadIdx.x * 8;
  float4 a = *(float4*)(data + base);
  float4 b = *(float4*)(data + base + 4);
  a.x = fmaxf(fmaf(a.x, sc, sh), 0.f);
  a.y = fmaxf(fmaf(a.y, sc, sh), 0.f);
  a.z = fmaxf(fmaf(a.z, sc, sh), 0.f);
  a.w = fmaxf(fmaf(a.w, sc, sh), 0.f);
  b.x = fmaxf(fmaf(b.x, sc, sh), 0.f);
  b.y = fmaxf(fmaf(b.y, sc, sh), 0.f);
  b.z = fmaxf(fmaf(b.z, sc, sh), 0.f);
  b.w = fmaxf(fmaf(b.w, sc, sh), 0.f);
  *(float4*)(data + base)     = a;
  *(float4*)(data + base + 4) = b;
}

__global__ __launch_bounds__(256)
void scale_bf16_kernel(const __hip_bfloat16* __restrict__ cvin,
                       const float* __restrict__ ss, float* __restrict__ out) {
  const int blk = blockIdx.x;
  const int ch = (blk >> 6) & 63;
  const float sc = ss[ch];
  const float sh = ss[COUT + ch];
  const int base = blk * 2048 + threadIdx.x * 8;
  union { v8s v; unsigned short h[8]; } u;
  u.v = *(const v8s*)(cvin + base);
  float r[8];
#pragma unroll
  for (int i = 0; i < 8; ++i)
    r[i] = fmaxf(fmaf(bf2f(u.h[i]), sc, sh), 0.f);
  *(float4*)(out + base)     = make_float4(r[0], r[1], r[2], r[3]);
  *(float4*)(out + base + 4) = make_float4(r[4], r[5], r[6], r[7]);
}

extern "C" void kernel_launch(void* const* d_in, const int* in_sizes, int n_in,
                              void* d_out, int out_size, void* d_ws, size_t ws_size,
                              hipStream_t stream) {
  const float* x      = (const float*)d_in[0];
  const float* coords = (const float*)d_in[1];
  const float* W      = (const float*)d_in[2];
  // d_in[3] = bias: cancels under training-mode BatchNorm; unused.
  const float* gamma  = (const float*)d_in[4];
  const float* beta   = (const float*)d_in[5];
  float* out = (float*)d_out;
  char* ws = (char*)d_ws;

  float* stat_sum = (float*)(ws);            // 64*256 f32 = 65536 B
  float* stat_sq  = (float*)(ws + 65536);    // 65536 B
  float* ss       = (float*)(ws + 131072);   // 128 f32
  v8s*   Wt       = (v8s*)(ws + 131584);     // 73728 B
  __hip_bfloat16* scratch = (__hip_bfloat16*)(ws + 262144); // 64 MiB (optional)

  const size_t need_bf16 = (size_t)262144 + (size_t)NB * COUT * LSEQ * 2;
  const bool bf16_path = ws_size >= need_bf16;

  hipMemsetAsync(ws, 0, 132096, stream);
  wtrans_kernel<<<18, 256, 0, stream>>>(W, Wt);

  if (bf16_path) {
    conv_kernel<__hip_bfloat16><<<GRIDC, 256, 0, stream>>>(
        x, coords, Wt, scratch, stat_sum, stat_sq);
    finalize_kernel<<<1, COUT, 0, stream>>>(stat_sum, stat_sq, gamma, beta, ss);
    scale_bf16_kernel<<<(NB * COUT * (LSEQ / 2048)), 256, 0, stream>>>(scratch, ss, out);
  } else {
    conv_kernel<float><<<GRIDC, 256, 0, stream>>>(
        x, coords, Wt, out, stat_sum, stat_sq);
    finalize_kernel<<<1, COUT, 0, stream>>>(stat_sum, stat_sq, gamma, beta, ss);
    scale_f32_kernel<<<(NB * COUT * (LSEQ / 2048)), 256, 0, stream>>>(out, ss);
  }
}